// Round 6
// baseline (449.801 us; speedup 1.0000x reference)
//
#include <hip/hip_runtime.h>

#define B_   2
#define H_   16
#define HK_  4
#define G_   4
#define S_   2048
#define D_   128
#define I_   2048

#define BM   128          // S-rows per output tile (32 per wave, rt=2)
#define TPB  512          // 8 waves: waves 0-3 -> I-half 0, waves 4-7 -> I-half 1
#define NIT  32           // total I tiles of 64 (16 per half)

static constexpr float SCALE = 0.08838834764831845f;  // 1/sqrt(128)

typedef _Float16 h8v __attribute__((ext_vector_type(8)));
typedef _Float16 h4v __attribute__((ext_vector_type(4)));
typedef float    f4v __attribute__((ext_vector_type(4)));

#define FRAG_PER_KH (I_ * D_)   // 262144 f16 per kv-head per tensor

// ---------------- prologue: build fragment-ready Kf/Uf/Vf ----------------
// Kf/Uf chunk layout (per kh): [it(32)][ct(4)][ks(4)][lane(64)][8 f16]
//   lane(m16=l&15, qq=l>>4) holds K[i = it*64+ct*16+m16][d = ks*32+qq*8 .. +8]
//   == A-operand frag of mfma_f32_16x16x32_f16 for the M^T=K*Q^T product.
//   per-it span: 4*4*64*8 = 8192 f16.
// Vf chunk layout (per kh): [it(32)][p(2)][dt(8)][lane(64)][8 f16]
//   lane holds, for c2=0,1: V[i = it*64+(p*2+c2)*16+qq*4 .. +4][d = dt*16+m16]
//   == packed pair of B-operand frags of mfma_f32_16x16x16f16 for O=A*V.
//   per-it span: 2*8*64*8 = 8192 f16.
__global__ __launch_bounds__(256) void prep(const float* __restrict__ Kg,
                                            const float* __restrict__ Ug,
                                            const float* __restrict__ Vg,
                                            _Float16* __restrict__ Kf,
                                            _Float16* __restrict__ Uf,
                                            _Float16* __restrict__ Vf) {
    const int bid = blockIdx.x;
    const int tid = threadIdx.x;
    if (bid < 1024) {
        const int c   = (bid & 511) * 256 + tid;   // chunk id, [0, 131072)
        const int kh  = c >> 15;
        const int r   = c & 32767;
        const int it  = r >> 10;
        const int ct  = (r >> 8) & 3;
        const int ks  = (r >> 6) & 3;
        const int l   = r & 63;
        const int m16 = l & 15, qq = l >> 4;
        const int i   = it * 64 + ct * 16 + m16;
        const int d   = ks * 32 + qq * 8;
        const float* src = ((bid < 512) ? Kg : Ug) + (size_t)(kh * I_ + i) * D_ + d;
        const float4 a = *(const float4*)src;
        const float4 bb = *(const float4*)(src + 4);
        h8v v;
        v[0]=(_Float16)a.x;  v[1]=(_Float16)a.y;  v[2]=(_Float16)a.z;  v[3]=(_Float16)a.w;
        v[4]=(_Float16)bb.x; v[5]=(_Float16)bb.y; v[6]=(_Float16)bb.z; v[7]=(_Float16)bb.w;
        *(h8v*)(((bid < 512) ? Kf : Uf) + (size_t)c * 8) = v;
    } else {
        const int c   = (bid - 1024) * 256 + tid;  // [0, 131072)
        const int kh  = c >> 15;
        const int r   = c & 32767;
        const int it  = r >> 10;
        const int p   = (r >> 9) & 1;
        const int dt  = (r >> 6) & 7;
        const int l   = r & 63;
        const int m16 = l & 15, qq = l >> 4;
        const int d   = dt * 16 + m16;
        h8v v;
#pragma unroll
        for (int c2 = 0; c2 < 2; ++c2) {
            const int i = it * 64 + (p * 2 + c2) * 16 + qq * 4;
#pragma unroll
            for (int jj = 0; jj < 4; ++jj)
                v[c2 * 4 + jj] = (_Float16)Vg[(size_t)(kh * I_ + i + jj) * D_ + d];
        }
        *(h8v*)(Vf + (size_t)c * 8) = v;
    }
}

// ---------------- main fused kernel: split-I across wave halves ----------------
__global__ __launch_bounds__(TPB, 4) void flashmlp_kernel(
    const float* __restrict__ Qg,
    const _Float16* __restrict__ Kf,
    const _Float16* __restrict__ Uf,
    const _Float16* __restrict__ Vf,
    float* __restrict__ Og)
{
    // 64 KB LDS used ONLY in the epilogue partial-sum combine (2 blocks/CU -> 128/160 KB)
    __shared__ f4v red[4096];   // [wv(4)][lane(64)][rt*8+dt(16)]

    // XCD swizzle: xcd = bid&7 -> kv-head = xcd>>1 (head's ~1.5MB f16 frags live in XCD L2)
    const int bid   = blockIdx.x;                 // 0..511
    const int xcd   = bid & 7;
    const int kh    = xcd >> 1;
    const int j     = ((bid >> 3) << 1) | (xcd & 1);
    const int stile = j & 15;
    const int bg    = j >> 4;
    const int b     = bg >> 2;
    const int g     = bg & 3;
    const int h     = kh * G_ + g;

    const int tid   = threadIdx.x;
    const int wave  = tid >> 6;       // 0..7
    const int wv    = wave & 3;       // row-block within tile
    const int ihalf = wave >> 2;      // which I-half this wave sums
    const int l     = tid & 63;
    const int m16   = l & 15;
    const int qq    = l >> 4;

    const size_t qbase = ((size_t)(b * H_ + h) * S_ + (size_t)stile * BM) * D_;

    // ---- Q fragments (B-operand of M^T), pre-scaled by 1/sqrt(D); 32 rows/wave
    h8v qf[2][4];
#pragma unroll
    for (int rt = 0; rt < 2; ++rt) {
        const float* qp = Qg + qbase + (size_t)(wv * 32 + rt * 16 + m16) * D_;
#pragma unroll
        for (int ks = 0; ks < 4; ++ks) {
            const float4 a = *(const float4*)(qp + ks * 32 + qq * 8);
            const float4 c = *(const float4*)(qp + ks * 32 + qq * 8 + 4);
            h8v v;
            v[0] = (_Float16)(a.x * SCALE); v[1] = (_Float16)(a.y * SCALE);
            v[2] = (_Float16)(a.z * SCALE); v[3] = (_Float16)(a.w * SCALE);
            v[4] = (_Float16)(c.x * SCALE); v[5] = (_Float16)(c.y * SCALE);
            v[6] = (_Float16)(c.z * SCALE); v[7] = (_Float16)(c.w * SCALE);
            qf[rt][ks] = v;
        }
    }

    f4v acc[2][8];
#pragma unroll
    for (int rt = 0; rt < 2; ++rt)
#pragma unroll
        for (int dt = 0; dt < 8; ++dt)
            acc[rt][dt] = f4v{0.f, 0.f, 0.f, 0.f};

    // wave-uniform frag bases + lane offset
    const _Float16* kb = Kf + (size_t)kh * FRAG_PER_KH + l * 8;
    const _Float16* ub = Uf + (size_t)kh * FRAG_PER_KH + l * 8;
    const _Float16* vb = Vf + (size_t)kh * FRAG_PER_KH + l * 8;

    const int it0 = ihalf * (NIT / 2);
    for (int it = it0; it < it0 + NIT / 2; ++it) {
        const _Float16* kp = kb + (size_t)it * 8192;
        const _Float16* up = ub + (size_t)it * 8192;

        // ---- M^T = K Q^T, N^T = U Q^T (swapped operands; D[m=i][n=s])
        f4v am[2][4], an[2][4];
#pragma unroll
        for (int ct = 0; ct < 4; ++ct) {
            h8v kf[4], uf[4];
#pragma unroll
            for (int ks = 0; ks < 4; ++ks) {
                kf[ks] = *(const h8v*)(kp + (ct * 4 + ks) * 512);
                uf[ks] = *(const h8v*)(up + (ct * 4 + ks) * 512);
            }
#pragma unroll
            for (int rt = 0; rt < 2; ++rt) {
                am[rt][ct] = __builtin_amdgcn_mfma_f32_16x16x32_f16(kf[0], qf[rt][0], f4v{0.f,0.f,0.f,0.f}, 0, 0, 0);
                an[rt][ct] = __builtin_amdgcn_mfma_f32_16x16x32_f16(uf[0], qf[rt][0], f4v{0.f,0.f,0.f,0.f}, 0, 0, 0);
            }
#pragma unroll
            for (int ks = 1; ks < 4; ++ks)
#pragma unroll
                for (int rt = 0; rt < 2; ++rt) {
                    am[rt][ct] = __builtin_amdgcn_mfma_f32_16x16x32_f16(kf[ks], qf[rt][ks], am[rt][ct], 0, 0, 0);
                    an[rt][ct] = __builtin_amdgcn_mfma_f32_16x16x32_f16(uf[ks], qf[rt][ks], an[rt][ct], 0, 0, 0);
                }
        }

        // ---- gate in registers: A^T tile is directly the 16x16x16 A-operand
        h4v ag[2][4];
#pragma unroll
        for (int rt = 0; rt < 2; ++rt)
#pragma unroll
            for (int ct = 0; ct < 4; ++ct)
#pragma unroll
                for (int r = 0; r < 4; ++r) {
                    const float mv = am[rt][ct][r];
                    const float nv = an[rt][ct][r];
                    const float sg = __builtin_amdgcn_rcpf(1.f + __expf(-mv));
                    ag[rt][ct][r] = (_Float16)(mv * sg * nv);
                }

        // ---- O += A V; V B-frags fully coalesced from fragment-ready layout
        const _Float16* vp = vb + (size_t)it * 8192;
#pragma unroll
        for (int p = 0; p < 2; ++p) {
            h8v vv[8];
#pragma unroll
            for (int dt = 0; dt < 8; ++dt)
                vv[dt] = *(const h8v*)(vp + (p * 8 + dt) * 512);
#pragma unroll
            for (int dt = 0; dt < 8; ++dt) {
                const h4v vlo = {vv[dt][0], vv[dt][1], vv[dt][2], vv[dt][3]};
                const h4v vhi = {vv[dt][4], vv[dt][5], vv[dt][6], vv[dt][7]};
#pragma unroll
                for (int rt = 0; rt < 2; ++rt) {
                    acc[rt][dt] = __builtin_amdgcn_mfma_f32_16x16x16f16(ag[rt][p * 2 + 0], vlo, acc[rt][dt], 0, 0, 0);
                    acc[rt][dt] = __builtin_amdgcn_mfma_f32_16x16x16f16(ag[rt][p * 2 + 1], vhi, acc[rt][dt], 0, 0, 0);
                }
            }
        }
    }

    // ---- combine I-halves through LDS, then lower waves store
    if (ihalf == 1) {
        f4v* dst = &red[(wv * 64 + l) * 16];
#pragma unroll
        for (int rt = 0; rt < 2; ++rt)
#pragma unroll
            for (int dt = 0; dt < 8; ++dt)
                dst[rt * 8 + dt] = acc[rt][dt];
    }
    __syncthreads();
    if (ihalf == 0) {
        const f4v* src = &red[(wv * 64 + l) * 16];
#pragma unroll
        for (int rt = 0; rt < 2; ++rt) {
#pragma unroll
            for (int dt = 0; dt < 8; ++dt)
                acc[rt][dt] += src[rt * 8 + dt];
#pragma unroll
            for (int r = 0; r < 4; ++r) {
                const int row = stile * BM + wv * 32 + rt * 16 + qq * 4 + r;
                float* op = Og + ((size_t)(b * H_ + h) * S_ + row) * D_;
#pragma unroll
                for (int dt = 0; dt < 8; ++dt)
                    op[dt * 16 + m16] = acc[rt][dt][r];
            }
        }
    }
}

extern "C" void kernel_launch(void* const* d_in, const int* in_sizes, int n_in,
                              void* d_out, int out_size, void* d_ws, size_t ws_size,
                              hipStream_t stream) {
    const float* Q = (const float*)d_in[0];
    const float* K = (const float*)d_in[1];
    const float* U = (const float*)d_in[2];
    const float* V = (const float*)d_in[3];
    float* out = (float*)d_out;

    _Float16* Kf = (_Float16*)d_ws;
    _Float16* Uf = Kf + (size_t)HK_ * FRAG_PER_KH;
    _Float16* Vf = Uf + (size_t)HK_ * FRAG_PER_KH;   // 6 MB total in d_ws

    prep<<<dim3(1536), dim3(256), 0, stream>>>(K, U, V, Kf, Uf, Vf);

    const int grid = (S_ / BM) * B_ * H_;   // 512 blocks, 2/CU -> 16 waves/CU
    flashmlp_kernel<<<dim3(grid), dim3(TPB), 0, stream>>>(Q, Kf, Uf, Vf, out);
}